// Round 2
// baseline (116.863 us; speedup 1.0000x reference)
//
#include <hip/hip_runtime.h>

typedef __attribute__((ext_vector_type(4))) float  float4v;
typedef __attribute__((ext_vector_type(4))) short  short4v;
typedef __attribute__((ext_vector_type(8))) short  short8v;
typedef __attribute__((ext_vector_type(4))) float  f32x4;

__device__ __forceinline__ unsigned short f2bf(float f) {
    unsigned int u = __float_as_uint(f);
    u += 0x7FFFu + ((u >> 16) & 1u);   // RNE
    return (unsigned short)(u >> 16);
}

__device__ __forceinline__ int swzb(int row, int kbyte) {
    // row-major [R][128] bf16 rows (256B); XOR-swizzle bits 4-6 to kill
    // the stride-256B bank conflict on ds_read_b128 (G4).
    return row * 256 + (kbyte ^ ((row & 7) << 4));
}

// ---------------- K0: transpose + bf16-cast weights into ws ----------------
__global__ void prep_weights(const float* __restrict__ cw1, const float* __restrict__ cw2,
                             const float* __restrict__ hw1, const float* __restrict__ hw2,
                             unsigned short* __restrict__ w1bT, unsigned short* __restrict__ w2bT,
                             unsigned short* __restrict__ hw1T, unsigned short* __restrict__ hw2T) {
    int i = blockIdx.x * 256 + threadIdx.x;
    if (i < 16384) {                       // w1 top half transposed: [j<128][k<128]
        int j = i >> 7, k = i & 127;
        w1bT[i] = f2bf(cw1[k * 128 + j]);
    } else if (i < 24576) {                // w2 transposed: [j<64][k<128]
        int t = i - 16384; int j = t >> 7, k = t & 127;
        w2bT[t] = f2bf(cw2[k * 64 + j]);
    } else if (i < 28672) {                // hw1 top 128 rows transposed: [j<32][k<128]
        int t = i - 24576; int j = t >> 7, k = t & 127;
        hw1T[t] = f2bf(hw1[k * 32 + j]);
    } else if (i < 29184) {                // hw2 transposed: [j<16][k<32]
        int t = i - 28672; int j = t >> 5, k = t & 31;
        hw2T[t] = f2bf(hw2[k * 16 + j]);
    }
}

// ---------------- K1: fused per-(b,t) kernel ----------------
__global__ __launch_bounds__(256, 2) void fused_main(
    const float* __restrict__ pos_g, const float* __restrict__ ctx_g,
    const float* __restrict__ dep_g,
    const float* __restrict__ cw1,  const float* __restrict__ cb1,
    const float* __restrict__ cb2,  const float* __restrict__ cw3,
    const float* __restrict__ cb3,  const float* __restrict__ hw1,
    const float* __restrict__ hb1,  const float* __restrict__ hb2,
    const float* __restrict__ hw3,  const float* __restrict__ hb3,
    const unsigned short* __restrict__ w1bT, const unsigned short* __restrict__ w2bT,
    const unsigned short* __restrict__ hw1T, const unsigned short* __restrict__ hw2T,
    float* __restrict__ out)
{
    __shared__ __align__(16) short posB[64 * 128];   // bf16 positions, swizzled
    __shared__ __align__(16) short h1B[64 * 128];    // bf16 layer1 out / later g1 (64x32 @64B rows)
    __shared__ __align__(16) short wbuf[128 * 128];  // phase1: w1bT; phase2: w2bT(0..16KB) + hw1T(@16KB)
    __shared__ __align__(16) short hw2s[16 * 32];    // 16 rows x 64B, swizzled (r&3)<<4
    __shared__ float ctxf[128], ctxW1v[128];
    __shared__ float tdep[64], diag[64];
    __shared__ float localc[64], ctxc[64], hierc[64];
    __shared__ float u1[32], cb2s[64], cw3s[64], hb1s[32], hb2s[16], hw3s[16];

    const int bt  = blockIdx.x;
    const int tid = threadIdx.x;
    const int lane = tid & 63;
    const int w   = tid >> 6;
    const int lr  = lane & 15;   // frag row-in-16 / output col
    const int lk  = lane >> 4;   // k-subgroup (8 bf16 each)
    const int R   = w * 16;      // this wave's output row base

    // ---------------- staging ----------------
    const float4v* pos4 = (const float4v*)(pos_g + (size_t)bt * 8192);
#pragma unroll
    for (int i = 0; i < 8; ++i) {
        int c = tid + 256 * i;           // 2048 float4 chunks
        int row = c >> 5, c4 = c & 31;
        float4v v = pos4[c];
        short4v b;
        b[0] = (short)f2bf(v[0]); b[1] = (short)f2bf(v[1]);
        b[2] = (short)f2bf(v[2]); b[3] = (short)f2bf(v[3]);
        *(short4v*)((char*)posB + row * 256 + ((c4 * 8) ^ ((row & 7) << 4))) = b;
    }
#pragma unroll
    for (int i = 0; i < 8; ++i) {        // w1bT: 2048 x 16B chunks, 16 chunks per 256B row
        int c = tid + 256 * i;
        int row = c >> 4, cb = (c & 15) * 16;
        *(short8v*)((char*)wbuf + swzb(row, cb)) = ((const short8v*)w1bT)[c];
    }
    if (tid < 128) ctxf[tid] = ctx_g[bt * 128 + tid];
    if (tid < 64)  tdep[tid] = tanhf(dep_g[bt * 64 + tid]);
    if (tid < 32)  { u1[tid] = hw1[128 * 32 + tid]; hb1s[tid] = hb1[tid]; }
    if (tid >= 64 && tid < 128) { cb2s[tid - 64] = cb2[tid - 64]; cw3s[tid - 64] = cw3[tid - 64]; }
    if (tid >= 128 && tid < 144) { hb2s[tid - 128] = hb2[tid - 128]; hw3s[tid - 128] = hw3[tid - 128]; }
    for (int i = tid; i < 512; i += 256) {   // hw2T -> LDS (swizzled, 64B rows)
        int j = i >> 5, k = i & 31;
        *(short*)((char*)hw2s + j * 64 + ((2 * k) ^ ((j & 3) << 4))) = (short)hw2T[i];
    }
    __syncthreads();

    // ---------------- Gram = P @ P^T (64x64), diag = |p|^2 ----------------
    f32x4 g0 = {0.f,0.f,0.f,0.f}, g1t = {0.f,0.f,0.f,0.f},
          g2t = {0.f,0.f,0.f,0.f}, g3t = {0.f,0.f,0.f,0.f};
#pragma unroll
    for (int ks = 0; ks < 4; ++ks) {
        int kb = ks * 64 + lk * 16;
        short8v a = *(const short8v*)((const char*)posB + swzb(R + lr, kb));
        short8v b0 = *(const short8v*)((const char*)posB + swzb(0  + lr, kb));
        short8v b1 = *(const short8v*)((const char*)posB + swzb(16 + lr, kb));
        short8v b2 = *(const short8v*)((const char*)posB + swzb(32 + lr, kb));
        short8v b3 = *(const short8v*)((const char*)posB + swzb(48 + lr, kb));
        g0 = __builtin_amdgcn_mfma_f32_16x16x32_bf16(a, b0, g0, 0, 0, 0);
        g1t = __builtin_amdgcn_mfma_f32_16x16x32_bf16(a, b1, g1t, 0, 0, 0);
        g2t = __builtin_amdgcn_mfma_f32_16x16x32_bf16(a, b2, g2t, 0, 0, 0);
        g3t = __builtin_amdgcn_mfma_f32_16x16x32_bf16(a, b3, g3t, 0, 0, 0);
    }
    {   // diagonal: rows of this wave live in tile jt==w; static-select (rule #20)
        f32x4 gw = (w == 0) ? g0 : (w == 1) ? g1t : (w == 2) ? g2t : g3t;
        int e = lr & 3;
        float dv = (e == 0) ? gw[0] : (e == 1) ? gw[1] : (e == 2) ? gw[2] : gw[3];
        if (lk == (lr >> 2)) diag[R + lr] = dv;
    }
    __syncthreads();

    // ---------------- local curvature: 3-NN mean dist ----------------
    {
        float s0[4], s1[4], s2[4], s3[4];
#pragma unroll
        for (int e = 0; e < 4; ++e) {
            int p = R + 4 * lk + e;
            float dp = diag[p];
            s0[e] = s1[e] = s2[e] = s3[e] = 1e30f;
#pragma unroll
            for (int jt = 0; jt < 4; ++jt) {
                f32x4 gt = (jt == 0) ? g0 : (jt == 1) ? g1t : (jt == 2) ? g2t : g3t;
                float gv = (e == 0) ? gt[0] : (e == 1) ? gt[1] : (e == 2) ? gt[2] : gt[3];
                float d2 = dp + diag[jt * 16 + lr] - 2.f * gv;
                float c0 = fminf(s0[e], d2), m0 = fmaxf(s0[e], d2);
                float c1 = fminf(s1[e], m0), m1 = fmaxf(s1[e], m0);
                float c2 = fminf(s2[e], m1), m2 = fmaxf(s2[e], m1);
                float c3 = fminf(s3[e], m2);
                s0[e] = c0; s1[e] = c1; s2[e] = c2; s3[e] = c3;
            }
        }
#pragma unroll
        for (int m = 1; m <= 8; m <<= 1) {
#pragma unroll
            for (int e = 0; e < 4; ++e) {
                float t0 = __shfl_xor(s0[e], m);
                float t1 = __shfl_xor(s1[e], m);
                float t2 = __shfl_xor(s2[e], m);
                float t3 = __shfl_xor(s3[e], m);
                float r0 = fminf(s0[e], t3), r1 = fminf(s1[e], t2);
                float r2 = fminf(s2[e], t1), r3 = fminf(s3[e], t0);
                float a0 = fminf(r0, r2), b0 = fmaxf(r0, r2);
                float a1 = fminf(r1, r3), b1 = fmaxf(r1, r3);
                s0[e] = fminf(a0, a1); s1[e] = fmaxf(a0, a1);
                s2[e] = fminf(b0, b1); s3[e] = fmaxf(b0, b1);
            }
        }
        if (lr == 0) {
#pragma unroll
            for (int e = 0; e < 4; ++e) {
                float d1 = sqrtf(fmaxf(s1[e], 1e-12f));
                float d2 = sqrtf(fmaxf(s2[e], 1e-12f));
                float d3 = sqrtf(fmaxf(s3[e], 1e-12f));
                float mean = (d1 + d2 + d3) * (1.f / 3.f);
                localc[R + 4 * lk + e] = -2.f * tanhf(1.f / (mean + 1e-6f));
            }
        }
    }

    // ---------------- ctx @ W1_bot + cb1 (f32, exact) ----------------
    if (tid < 128) {
        int j = tid;
        float a0 = cb1[j], a1 = 0.f, a2 = 0.f, a3 = 0.f;
        for (int d = 0; d < 128; d += 4) {
            a0 += ctxf[d + 0] * cw1[(128 + d) * 128 + j];
            a1 += ctxf[d + 1] * cw1[(129 + d) * 128 + j];
            a2 += ctxf[d + 2] * cw1[(130 + d) * 128 + j];
            a3 += ctxf[d + 3] * cw1[(131 + d) * 128 + j];
        }
        ctxW1v[j] = (a0 + a1) + (a2 + a3);
    }
    __syncthreads();

    // ---------------- layer1: H1 = relu(P@W1_top + ctxW1) ----------------
    {
        f32x4 h[8];
#pragma unroll
        for (int jt = 0; jt < 8; ++jt) h[jt] = (f32x4){0.f,0.f,0.f,0.f};
#pragma unroll
        for (int ks = 0; ks < 4; ++ks) {
            int kb = ks * 64 + lk * 16;
            short8v a = *(const short8v*)((const char*)posB + swzb(R + lr, kb));
#pragma unroll
            for (int jt = 0; jt < 8; ++jt) {
                short8v b = *(const short8v*)((const char*)wbuf + swzb(jt * 16 + lr, kb));
                h[jt] = __builtin_amdgcn_mfma_f32_16x16x32_bf16(a, b, h[jt], 0, 0, 0);
            }
        }
#pragma unroll
        for (int jt = 0; jt < 8; ++jt) {
            int j = jt * 16 + lr;
            float add = ctxW1v[j];
#pragma unroll
            for (int e = 0; e < 4; ++e) {
                int p = R + 4 * lk + e;
                float v = fmaxf(h[jt][e] + add, 0.f);
                *(short*)((char*)h1B + p * 256 + ((2 * j) ^ ((p & 7) << 4))) = (short)f2bf(v);
            }
        }
    }
    __syncthreads();

    // ---------------- reload wbuf: w2bT + hw1T ----------------
#pragma unroll
    for (int i = 0; i < 4; ++i) {
        int c = tid + 256 * i;               // 1024 chunks, 16 per 256B row
        int row = c >> 4, cb = (c & 15) * 16;
        *(short8v*)((char*)wbuf + swzb(row, cb)) = ((const short8v*)w2bT)[c];
    }
#pragma unroll
    for (int i = 0; i < 2; ++i) {
        int c = tid + 256 * i;               // 512 chunks, 16 per 256B row
        int row = c >> 4, cb = (c & 15) * 16;
        *(short8v*)((char*)wbuf + 16384 + swzb(row, cb)) = ((const short8v*)hw1T)[c];
    }
    __syncthreads();

    // ---------------- layer2 + layer3 (ctx path), fused reduce ----------------
    {
        f32x4 h2[4];
#pragma unroll
        for (int jt = 0; jt < 4; ++jt) h2[jt] = (f32x4){0.f,0.f,0.f,0.f};
#pragma unroll
        for (int ks = 0; ks < 4; ++ks) {
            int kb = ks * 64 + lk * 16;
            short8v a = *(const short8v*)((const char*)h1B + swzb(R + lr, kb));
#pragma unroll
            for (int jt = 0; jt < 4; ++jt) {
                short8v b = *(const short8v*)((const char*)wbuf + swzb(jt * 16 + lr, kb));
                h2[jt] = __builtin_amdgcn_mfma_f32_16x16x32_bf16(a, b, h2[jt], 0, 0, 0);
            }
        }
        float s[4] = {0.f, 0.f, 0.f, 0.f};
#pragma unroll
        for (int jt = 0; jt < 4; ++jt) {
            int j = jt * 16 + lr;
            float wj = cw3s[j], bj = cb2s[j];
#pragma unroll
            for (int e = 0; e < 4; ++e) s[e] += fmaxf(h2[jt][e] + bj, 0.f) * wj;
        }
#pragma unroll
        for (int m = 1; m <= 8; m <<= 1) {
#pragma unroll
            for (int e = 0; e < 4; ++e) s[e] += __shfl_xor(s[e], m);
        }
        float cb3v = cb3[0];
        if (lr == 0) {
#pragma unroll
            for (int e = 0; e < 4; ++e) ctxc[R + 4 * lk + e] = s[e] + cb3v;
        }
    }

    // ---------------- hierarchy layer1 MFMA ----------------
    f32x4 q0 = {0.f,0.f,0.f,0.f}, q1 = {0.f,0.f,0.f,0.f};
#pragma unroll
    for (int ks = 0; ks < 4; ++ks) {
        int kb = ks * 64 + lk * 16;
        short8v a = *(const short8v*)((const char*)posB + swzb(R + lr, kb));
        short8v b0 = *(const short8v*)((const char*)wbuf + 16384 + swzb(0  + lr, kb));
        short8v b1 = *(const short8v*)((const char*)wbuf + 16384 + swzb(16 + lr, kb));
        q0 = __builtin_amdgcn_mfma_f32_16x16x32_bf16(a, b0, q0, 0, 0, 0);
        q1 = __builtin_amdgcn_mfma_f32_16x16x32_bf16(a, b1, q1, 0, 0, 0);
    }
    __syncthreads();   // everyone done reading h1B (layer2) before overwrite

    {   // G1 = relu(. + tanh(depth)*u1 + hb1) -> bf16 LDS [64][32] (64B rows)
#pragma unroll
        for (int jt = 0; jt < 2; ++jt) {
            int j = jt * 16 + lr;
            float uj = u1[j], bj = hb1s[j];
#pragma unroll
            for (int e = 0; e < 4; ++e) {
                int p = R + 4 * lk + e;
                f32x4 qq = (jt == 0) ? q0 : q1;
                float qv = (e == 0) ? qq[0] : (e == 1) ? qq[1] : (e == 2) ? qq[2] : qq[3];
                float v = fmaxf(qv + tdep[p] * uj + bj, 0.f);
                *(short*)((char*)h1B + p * 64 + ((2 * j) ^ ((p & 3) << 4))) = (short)f2bf(v);
            }
        }
    }
    __syncthreads();

    {   // hier layer2 (K=32) + tanh + layer3 reduce
        f32x4 g2 = {0.f,0.f,0.f,0.f};
        int p = R + lr;
        short8v a = *(const short8v*)((const char*)h1B + p * 64 + ((lk * 16) ^ ((p & 3) << 4)));
        short8v b = *(const short8v*)((const char*)hw2s + lr * 64 + ((lk * 16) ^ ((lr & 3) << 4)));
        g2 = __builtin_amdgcn_mfma_f32_16x16x32_bf16(a, b, g2, 0, 0, 0);
        float sh[4];
        float bj = hb2s[lr], wj = hw3s[lr];
#pragma unroll
        for (int e = 0; e < 4; ++e) sh[e] = tanhf(g2[e] + bj) * wj;
#pragma unroll
        for (int m = 1; m <= 8; m <<= 1) {
#pragma unroll
            for (int e = 0; e < 4; ++e) sh[e] += __shfl_xor(sh[e], m);
        }
        float hb3v = hb3[0];
        if (lr == 0) {
#pragma unroll
            for (int e = 0; e < 4; ++e) hierc[R + 4 * lk + e] = sh[e] + hb3v;
        }
    }
    __syncthreads();

    if (tid < 64) {
        float comb = 0.5f * localc[tid] + 0.3f * ctxc[tid] + 0.2f * hierc[tid];
        out[bt * 64 + tid] = comb;
    }
}

// ---------------- K2a: per-16-bt partial sums over p ----------------
__global__ void reduce1(const float* __restrict__ comb, float* __restrict__ partials) {
    __shared__ float sm[256];
    int b = blockIdx.x, tid = threadIdx.x;
    const float* src = comb + (size_t)b * 1024;
    float s = 0.f;
#pragma unroll
    for (int k = 0; k < 4; ++k) s += src[tid + 256 * k];
    sm[tid] = s;
    __syncthreads();
    if (tid < 64) partials[b * 64 + tid] = sm[tid] + sm[tid + 64] + sm[tid + 128] + sm[tid + 192];
}

// ---------------- K2b: final mean + memory update ----------------
__global__ void reduce2(const float* __restrict__ partials, const float* __restrict__ mem,
                        float* __restrict__ newmem) {
    int p = threadIdx.x;  // 64 threads
    float s = 0.f;
    for (int b = 0; b < 256; ++b) s += partials[b * 64 + p];
    newmem[p] = 0.9f * mem[p] + 0.1f * (s * (1.f / 4096.f));
}

// ---------------- K3: in-place smoothing + clip ----------------
__global__ void finalize(float* __restrict__ out, const float* __restrict__ newmem) {
    int i = blockIdx.x * 256 + threadIdx.x;
    float nm = newmem[i & 63];
    float v = 0.9f * out[i] + 0.1f * nm;
    out[i] = fminf(fmaxf(v, -5.f), 2.f);
}

extern "C" void kernel_launch(void* const* d_in, const int* in_sizes, int n_in,
                              void* d_out, int out_size, void* d_ws, size_t ws_size,
                              hipStream_t stream) {
    (void)in_sizes; (void)n_in; (void)out_size; (void)ws_size;
    const float* pos = (const float*)d_in[0];
    const float* ctx = (const float*)d_in[1];
    const float* dep = (const float*)d_in[2];
    const float* cw1 = (const float*)d_in[3];
    const float* cb1 = (const float*)d_in[4];
    const float* cw2 = (const float*)d_in[5];
    const float* cb2 = (const float*)d_in[6];
    const float* cw3 = (const float*)d_in[7];
    const float* cb3 = (const float*)d_in[8];
    const float* hw1 = (const float*)d_in[9];
    const float* hb1 = (const float*)d_in[10];
    const float* hw2 = (const float*)d_in[11];
    const float* hb2 = (const float*)d_in[12];
    const float* hw3 = (const float*)d_in[13];
    const float* hb3 = (const float*)d_in[14];
    const float* cmem = (const float*)d_in[15];
    float* out = (float*)d_out;
    float* ws = (float*)d_ws;
    float* partials = ws;                         // 256*64
    float* newmem = ws + 16384;                   // 64
    unsigned short* wT = (unsigned short*)(ws + 16448);
    unsigned short* w1bT = wT;                    // 16384
    unsigned short* w2bT = wT + 16384;            // 8192
    unsigned short* hw1T = wT + 24576;            // 4096
    unsigned short* hw2T = wT + 28672;            // 512

    prep_weights<<<114, 256, 0, stream>>>(cw1, cw2, hw1, hw2, w1bT, w2bT, hw1T, hw2T);
    fused_main<<<4096, 256, 0, stream>>>(pos, ctx, dep, cw1, cb1, cb2, cw3, cb3,
                                         hw1, hb1, hb2, hw3, hb3,
                                         w1bT, w2bT, hw1T, hw2T, out);
    reduce1<<<256, 256, 0, stream>>>(out, partials);
    reduce2<<<1, 64, 0, stream>>>(partials, cmem, newmem);
    finalize<<<1024, 256, 0, stream>>>(out, newmem);
}

// Round 3
// 99.397 us; speedup vs baseline: 1.1757x; 1.1757x over previous
//
#include <hip/hip_runtime.h>

typedef __attribute__((ext_vector_type(4))) float  float4v;
typedef __attribute__((ext_vector_type(4))) short  short4v;
typedef __attribute__((ext_vector_type(8))) short  short8v;
typedef __attribute__((ext_vector_type(4))) float  f32x4;

__device__ __forceinline__ unsigned short f2bf(float f) {
    unsigned int u = __float_as_uint(f);
    u += 0x7FFFu + ((u >> 16) & 1u);   // RNE
    return (unsigned short)(u >> 16);
}

__device__ __forceinline__ int swzb(int row, int kbyte) {
    // row-major [R][128] bf16 rows (256B); XOR-swizzle bits 4-6 (G4).
    return row * 256 + (kbyte ^ ((row & 7) << 4));
}
__device__ __forceinline__ int swzh(int row, int kbyte) {
    // h1B swizzle: extra (row&8)<<2 term spreads lk/lk+2 lanes onto
    // distinct banks -> conflict-free 2B writeout (2-way only, free).
    return row * 256 + (kbyte ^ ((row & 7) << 4) ^ ((row & 8) << 2));
}

// ---------------- K0: transpose + bf16-cast weights into ws ----------------
__global__ void prep_weights(const float* __restrict__ cw1, const float* __restrict__ cw2,
                             const float* __restrict__ hw1, const float* __restrict__ hw2,
                             unsigned short* __restrict__ w1bT, unsigned short* __restrict__ w2bT,
                             unsigned short* __restrict__ hw1T, unsigned short* __restrict__ hw2T) {
    int i = blockIdx.x * 256 + threadIdx.x;
    if (i < 16384) {                       // w1 top half transposed: [j<128][k<128]
        int j = i >> 7, k = i & 127;
        w1bT[i] = f2bf(cw1[k * 128 + j]);
    } else if (i < 24576) {                // w2 transposed: [j<64][k<128]
        int t = i - 16384; int j = t >> 7, k = t & 127;
        w2bT[t] = f2bf(cw2[k * 64 + j]);
    } else if (i < 28672) {                // hw1 top 128 rows transposed: [j<32][k<128]
        int t = i - 24576; int j = t >> 7, k = t & 127;
        hw1T[t] = f2bf(hw1[k * 32 + j]);
    } else if (i < 29184) {                // hw2 transposed: [j<16][k<32]
        int t = i - 28672; int j = t >> 5, k = t & 31;
        hw2T[t] = f2bf(hw2[k * 16 + j]);
    }
}

// ---------------- K1: fused per-(b,t) kernel ----------------
__global__ __launch_bounds__(256, 3) void fused_main(
    const float* __restrict__ pos_g, const float* __restrict__ ctx_g,
    const float* __restrict__ dep_g,
    const float* __restrict__ cw1,  const float* __restrict__ cb1,
    const float* __restrict__ cb2,  const float* __restrict__ cw3,
    const float* __restrict__ cb3,  const float* __restrict__ hw1,
    const float* __restrict__ hb1,  const float* __restrict__ hb2,
    const float* __restrict__ hw3,  const float* __restrict__ hb3,
    const unsigned short* __restrict__ w1bT, const unsigned short* __restrict__ w2bT,
    const unsigned short* __restrict__ hw1T, const unsigned short* __restrict__ hw2T,
    float* __restrict__ out)
{
    __shared__ __align__(16) short posB[64 * 128];   // bf16 positions, swizzled (16 KB)
    __shared__ __align__(16) short h1B[64 * 128];    // layer1 out / later g1 (16 KB)
    __shared__ __align__(16) short wbuf[64 * 128];   // 16 KB staging: w1a -> w1b -> w2 -> hw1
    __shared__ __align__(16) short hw2s[16 * 32];    // 1 KB, swizzled (r&3)<<4
    __shared__ float ctxf[128], ctxW1v[128];
    __shared__ float tdep[64], diag[64];
    __shared__ float localc[64], ctxc[64], hierc[64];
    __shared__ float u1[32], cb2s[64], cw3s[64], hb1s[32], hb2s[16], hw3s[16];

    const int bt  = blockIdx.x;
    const int tid = threadIdx.x;
    const int lane = tid & 63;
    const int w   = tid >> 6;
    const int lr  = lane & 15;   // frag row-in-16 / output col
    const int lk  = lane >> 4;   // k-subgroup (8 bf16 each)
    const int R   = w * 16;      // this wave's output row base

    // ---------------- phase 0: staging ----------------
    const float4v* pos4 = (const float4v*)(pos_g + (size_t)bt * 8192);
#pragma unroll
    for (int i = 0; i < 8; ++i) {
        int c = tid + 256 * i;           // 2048 float4 chunks
        int row = c >> 5, c4 = c & 31;
        float4v v = pos4[c];
        short4v b;
        b[0] = (short)f2bf(v[0]); b[1] = (short)f2bf(v[1]);
        b[2] = (short)f2bf(v[2]); b[3] = (short)f2bf(v[3]);
        *(short4v*)((char*)posB + row * 256 + ((c4 * 8) ^ ((row & 7) << 4))) = b;
    }
#pragma unroll
    for (int i = 0; i < 4; ++i) {        // w1bT rows 0..63 (first 1024 x 16B chunks)
        int c = tid + 256 * i;
        int row = c >> 4, cb = (c & 15) * 16;
        *(short8v*)((char*)wbuf + swzb(row, cb)) = ((const short8v*)w1bT)[c];
    }
    if (tid < 128) ctxf[tid] = ctx_g[bt * 128 + tid];
    if (tid < 64)  tdep[tid] = tanhf(dep_g[bt * 64 + tid]);
    if (tid < 32)  { u1[tid] = hw1[128 * 32 + tid]; hb1s[tid] = hb1[tid]; }
    if (tid >= 64 && tid < 128) { cb2s[tid - 64] = cb2[tid - 64]; cw3s[tid - 64] = cw3[tid - 64]; }
    if (tid >= 128 && tid < 144) { hb2s[tid - 128] = hb2[tid - 128]; hw3s[tid - 128] = hw3[tid - 128]; }
    for (int i = tid; i < 512; i += 256) {   // hw2T -> LDS (swizzled, 64B rows)
        int j = i >> 5, k = i & 31;
        *(short*)((char*)hw2s + j * 64 + ((2 * k) ^ ((j & 3) << 4))) = (short)hw2T[i];
    }
    __syncthreads();

    // ---------------- phase 2: Gram MFMA + ctx@W1_bot (parallel pipes) ----------
    f32x4 g0 = {0.f,0.f,0.f,0.f}, g1t = {0.f,0.f,0.f,0.f},
          g2t = {0.f,0.f,0.f,0.f}, g3t = {0.f,0.f,0.f,0.f};
#pragma unroll
    for (int ks = 0; ks < 4; ++ks) {
        int kb = ks * 64 + lk * 16;
        short8v a = *(const short8v*)((const char*)posB + swzb(R + lr, kb));
        short8v b0 = *(const short8v*)((const char*)posB + swzb(0  + lr, kb));
        short8v b1 = *(const short8v*)((const char*)posB + swzb(16 + lr, kb));
        short8v b2 = *(const short8v*)((const char*)posB + swzb(32 + lr, kb));
        short8v b3 = *(const short8v*)((const char*)posB + swzb(48 + lr, kb));
        g0 = __builtin_amdgcn_mfma_f32_16x16x32_bf16(a, b0, g0, 0, 0, 0);
        g1t = __builtin_amdgcn_mfma_f32_16x16x32_bf16(a, b1, g1t, 0, 0, 0);
        g2t = __builtin_amdgcn_mfma_f32_16x16x32_bf16(a, b2, g2t, 0, 0, 0);
        g3t = __builtin_amdgcn_mfma_f32_16x16x32_bf16(a, b3, g3t, 0, 0, 0);
    }
    {   // diagonal: rows of this wave live in tile jt==w; static-select (rule #20)
        f32x4 gw = (w == 0) ? g0 : (w == 1) ? g1t : (w == 2) ? g2t : g3t;
        int e = lr & 3;
        float dv = (e == 0) ? gw[0] : (e == 1) ? gw[1] : (e == 2) ? gw[2] : gw[3];
        if (lk == (lr >> 2)) diag[R + lr] = dv;
    }
    if (tid < 128) {      // ctx @ W1_bot + cb1 (f32, exact) — VALU/VMEM, overlaps MFMA
        int j = tid;
        float a0 = cb1[j], a1 = 0.f, a2 = 0.f, a3 = 0.f;
        for (int d = 0; d < 128; d += 4) {
            a0 += ctxf[d + 0] * cw1[(128 + d) * 128 + j];
            a1 += ctxf[d + 1] * cw1[(129 + d) * 128 + j];
            a2 += ctxf[d + 2] * cw1[(130 + d) * 128 + j];
            a3 += ctxf[d + 3] * cw1[(131 + d) * 128 + j];
        }
        ctxW1v[j] = (a0 + a1) + (a2 + a3);
    }
    __syncthreads();

    // ---------------- phase 3: layer1a MFMA (jt 0..3) + kNN (VALU) ----------------
    f32x4 h[8];
#pragma unroll
    for (int jt = 0; jt < 8; ++jt) h[jt] = (f32x4){0.f,0.f,0.f,0.f};
#pragma unroll
    for (int ks = 0; ks < 4; ++ks) {
        int kb = ks * 64 + lk * 16;
        short8v a = *(const short8v*)((const char*)posB + swzb(R + lr, kb));
#pragma unroll
        for (int jt = 0; jt < 4; ++jt) {
            short8v b = *(const short8v*)((const char*)wbuf + swzb(jt * 16 + lr, kb));
            h[jt] = __builtin_amdgcn_mfma_f32_16x16x32_bf16(a, b, h[jt], 0, 0, 0);
        }
    }
    {   // local curvature: 3-NN mean dist (registers + shuffles; overlaps MFMA pipe)
        float s0[4], s1[4], s2[4], s3[4];
#pragma unroll
        for (int e = 0; e < 4; ++e) {
            int p = R + 4 * lk + e;
            float dp = diag[p];
            s0[e] = s1[e] = s2[e] = s3[e] = 1e30f;
#pragma unroll
            for (int jt = 0; jt < 4; ++jt) {
                f32x4 gt = (jt == 0) ? g0 : (jt == 1) ? g1t : (jt == 2) ? g2t : g3t;
                float gv = (e == 0) ? gt[0] : (e == 1) ? gt[1] : (e == 2) ? gt[2] : gt[3];
                float d2 = dp + diag[jt * 16 + lr] - 2.f * gv;
                float c0 = fminf(s0[e], d2), m0 = fmaxf(s0[e], d2);
                float c1 = fminf(s1[e], m0), m1 = fmaxf(s1[e], m0);
                float c2 = fminf(s2[e], m1), m2 = fmaxf(s2[e], m1);
                float c3 = fminf(s3[e], m2);
                s0[e] = c0; s1[e] = c1; s2[e] = c2; s3[e] = c3;
            }
        }
#pragma unroll
        for (int m = 1; m <= 8; m <<= 1) {
#pragma unroll
            for (int e = 0; e < 4; ++e) {
                float t0 = __shfl_xor(s0[e], m);
                float t1 = __shfl_xor(s1[e], m);
                float t2 = __shfl_xor(s2[e], m);
                float t3 = __shfl_xor(s3[e], m);
                float r0 = fminf(s0[e], t3), r1 = fminf(s1[e], t2);
                float r2 = fminf(s2[e], t1), r3 = fminf(s3[e], t0);
                float a0 = fminf(r0, r2), b0 = fmaxf(r0, r2);
                float a1 = fminf(r1, r3), b1 = fmaxf(r1, r3);
                s0[e] = fminf(a0, a1); s1[e] = fmaxf(a0, a1);
                s2[e] = fminf(b0, b1); s3[e] = fmaxf(b0, b1);
            }
        }
        if (lr == 0) {
#pragma unroll
            for (int e = 0; e < 4; ++e) {
                float d1 = sqrtf(fmaxf(s1[e], 1e-12f));
                float d2 = sqrtf(fmaxf(s2[e], 1e-12f));
                float d3 = sqrtf(fmaxf(s3[e], 1e-12f));
                float mean = (d1 + d2 + d3) * (1.f / 3.f);
                localc[R + 4 * lk + e] = -2.f * tanhf(1.f / (mean + 1e-6f));
            }
        }
    }
    __syncthreads();   // all waves done with wbuf(w1a)

    // ---------------- phase 4: stage w1bT rows 64..127 ----------------
#pragma unroll
    for (int i = 0; i < 4; ++i) {
        int c = 1024 + tid + 256 * i;
        int row = (c >> 4) - 64, cb = (c & 15) * 16;
        *(short8v*)((char*)wbuf + swzb(row, cb)) = ((const short8v*)w1bT)[c];
    }
    __syncthreads();

    // ---------------- phase 5: layer1b MFMA (jt 4..7) + H1 writeout ----------------
#pragma unroll
    for (int ks = 0; ks < 4; ++ks) {
        int kb = ks * 64 + lk * 16;
        short8v a = *(const short8v*)((const char*)posB + swzb(R + lr, kb));
#pragma unroll
        for (int jt = 4; jt < 8; ++jt) {
            short8v b = *(const short8v*)((const char*)wbuf + swzb((jt - 4) * 16 + lr, kb));
            h[jt] = __builtin_amdgcn_mfma_f32_16x16x32_bf16(a, b, h[jt], 0, 0, 0);
        }
    }
#pragma unroll
    for (int jt = 0; jt < 8; ++jt) {
        int j = jt * 16 + lr;
        float add = ctxW1v[j];
#pragma unroll
        for (int e = 0; e < 4; ++e) {
            int p = R + 4 * lk + e;
            float v = fmaxf(h[jt][e] + add, 0.f);
            *(short*)((char*)h1B + swzh(p, 2 * j)) = (short)f2bf(v);
        }
    }
    __syncthreads();   // h1 visible; wbuf(w1b) free

    // ---------------- phase 6: stage w2bT ----------------
#pragma unroll
    for (int i = 0; i < 4; ++i) {
        int c = tid + 256 * i;               // 1024 chunks, 16 per 256B row
        int row = c >> 4, cb = (c & 15) * 16;
        *(short8v*)((char*)wbuf + swzb(row, cb)) = ((const short8v*)w2bT)[c];
    }
    __syncthreads();

    // ---------------- phase 7: layer2 + layer3 (ctx path), fused reduce ----------
    {
        f32x4 h2[4];
#pragma unroll
        for (int jt = 0; jt < 4; ++jt) h2[jt] = (f32x4){0.f,0.f,0.f,0.f};
#pragma unroll
        for (int ks = 0; ks < 4; ++ks) {
            int kb = ks * 64 + lk * 16;
            short8v a = *(const short8v*)((const char*)h1B + swzh(R + lr, kb));
#pragma unroll
            for (int jt = 0; jt < 4; ++jt) {
                short8v b = *(const short8v*)((const char*)wbuf + swzb(jt * 16 + lr, kb));
                h2[jt] = __builtin_amdgcn_mfma_f32_16x16x32_bf16(a, b, h2[jt], 0, 0, 0);
            }
        }
        float s[4] = {0.f, 0.f, 0.f, 0.f};
#pragma unroll
        for (int jt = 0; jt < 4; ++jt) {
            int j = jt * 16 + lr;
            float wj = cw3s[j], bj = cb2s[j];
#pragma unroll
            for (int e = 0; e < 4; ++e) s[e] += fmaxf(h2[jt][e] + bj, 0.f) * wj;
        }
#pragma unroll
        for (int m = 1; m <= 8; m <<= 1) {
#pragma unroll
            for (int e = 0; e < 4; ++e) s[e] += __shfl_xor(s[e], m);
        }
        float cb3v = cb3[0];
        if (lr == 0) {
#pragma unroll
            for (int e = 0; e < 4; ++e) ctxc[R + 4 * lk + e] = s[e] + cb3v;
        }
    }
    __syncthreads();   // h1B free, wbuf(w2) free

    // ---------------- phase 8: stage hw1T ----------------
#pragma unroll
    for (int i = 0; i < 2; ++i) {
        int c = tid + 256 * i;               // 512 chunks -> rows 0..31
        int row = c >> 4, cb = (c & 15) * 16;
        *(short8v*)((char*)wbuf + swzb(row, cb)) = ((const short8v*)hw1T)[c];
    }
    __syncthreads();

    // ---------------- phase 9: hierarchy layer1 MFMA + G1 writeout ----------------
    {
        f32x4 q0 = {0.f,0.f,0.f,0.f}, q1 = {0.f,0.f,0.f,0.f};
#pragma unroll
        for (int ks = 0; ks < 4; ++ks) {
            int kb = ks * 64 + lk * 16;
            short8v a = *(const short8v*)((const char*)posB + swzb(R + lr, kb));
            short8v b0 = *(const short8v*)((const char*)wbuf + swzb(0  + lr, kb));
            short8v b1 = *(const short8v*)((const char*)wbuf + swzb(16 + lr, kb));
            q0 = __builtin_amdgcn_mfma_f32_16x16x32_bf16(a, b0, q0, 0, 0, 0);
            q1 = __builtin_amdgcn_mfma_f32_16x16x32_bf16(a, b1, q1, 0, 0, 0);
        }
        // G1 = relu(. + tanh(depth)*u1 + hb1) -> bf16 LDS [64][32] (64B rows)
#pragma unroll
        for (int jt = 0; jt < 2; ++jt) {
            int j = jt * 16 + lr;
            float uj = u1[j], bj = hb1s[j];
#pragma unroll
            for (int e = 0; e < 4; ++e) {
                int p = R + 4 * lk + e;
                f32x4 qq = (jt == 0) ? q0 : q1;
                float qv = (e == 0) ? qq[0] : (e == 1) ? qq[1] : (e == 2) ? qq[2] : qq[3];
                float v = fmaxf(qv + tdep[p] * uj + bj, 0.f);
                *(short*)((char*)h1B + p * 64 + ((2 * j) ^ ((p & 3) << 4))) = (short)f2bf(v);
            }
        }
    }
    __syncthreads();

    // ---------------- phase 10: hier layer2 (K=32) + tanh + layer3 + combine ------
    {
        f32x4 g2 = {0.f,0.f,0.f,0.f};
        int p = R + lr;
        short8v a = *(const short8v*)((const char*)h1B + p * 64 + ((lk * 16) ^ ((p & 3) << 4)));
        short8v b = *(const short8v*)((const char*)hw2s + lr * 64 + ((lk * 16) ^ ((lr & 3) << 4)));
        g2 = __builtin_amdgcn_mfma_f32_16x16x32_bf16(a, b, g2, 0, 0, 0);
        float sh[4];
        float bj = hb2s[lr], wj = hw3s[lr];
#pragma unroll
        for (int e = 0; e < 4; ++e) sh[e] = tanhf(g2[e] + bj) * wj;
#pragma unroll
        for (int m = 1; m <= 8; m <<= 1) {
#pragma unroll
            for (int e = 0; e < 4; ++e) sh[e] += __shfl_xor(sh[e], m);
        }
        float hb3v = hb3[0];
        if (lr == 0) {
#pragma unroll
            for (int e = 0; e < 4; ++e) hierc[R + 4 * lk + e] = sh[e] + hb3v;
        }
    }
    __syncthreads();

    if (tid < 64) {
        float comb = 0.5f * localc[tid] + 0.3f * ctxc[tid] + 0.2f * hierc[tid];
        out[bt * 64 + tid] = comb;
    }
}

// ---------------- K2a: per-16-bt partial sums over p ----------------
__global__ void reduce1(const float* __restrict__ comb, float* __restrict__ partials) {
    __shared__ float sm[256];
    int b = blockIdx.x, tid = threadIdx.x;
    const float* src = comb + (size_t)b * 1024;
    float s = 0.f;
#pragma unroll
    for (int k = 0; k < 4; ++k) s += src[tid + 256 * k];
    sm[tid] = s;
    __syncthreads();
    if (tid < 64) partials[b * 64 + tid] = sm[tid] + sm[tid + 64] + sm[tid + 128] + sm[tid + 192];
}

// ---------------- K2b: final mean + memory update ----------------
__global__ void reduce2(const float* __restrict__ partials, const float* __restrict__ mem,
                        float* __restrict__ newmem) {
    int p = threadIdx.x;  // 64 threads
    float s = 0.f;
    for (int b = 0; b < 256; ++b) s += partials[b * 64 + p];
    newmem[p] = 0.9f * mem[p] + 0.1f * (s * (1.f / 4096.f));
}

// ---------------- K3: in-place smoothing + clip ----------------
__global__ void finalize(float* __restrict__ out, const float* __restrict__ newmem) {
    int i = blockIdx.x * 256 + threadIdx.x;
    float nm = newmem[i & 63];
    float v = 0.9f * out[i] + 0.1f * nm;
    out[i] = fminf(fmaxf(v, -5.f), 2.f);
}

extern "C" void kernel_launch(void* const* d_in, const int* in_sizes, int n_in,
                              void* d_out, int out_size, void* d_ws, size_t ws_size,
                              hipStream_t stream) {
    (void)in_sizes; (void)n_in; (void)out_size; (void)ws_size;
    const float* pos = (const float*)d_in[0];
    const float* ctx = (const float*)d_in[1];
    const float* dep = (const float*)d_in[2];
    const float* cw1 = (const float*)d_in[3];
    const float* cb1 = (const float*)d_in[4];
    const float* cw2 = (const float*)d_in[5];
    const float* cb2 = (const float*)d_in[6];
    const float* cw3 = (const float*)d_in[7];
    const float* cb3 = (const float*)d_in[8];
    const float* hw1 = (const float*)d_in[9];
    const float* hb1 = (const float*)d_in[10];
    const float* hw2 = (const float*)d_in[11];
    const float* hb2 = (const float*)d_in[12];
    const float* hw3 = (const float*)d_in[13];
    const float* hb3 = (const float*)d_in[14];
    const float* cmem = (const float*)d_in[15];
    float* out = (float*)d_out;
    float* ws = (float*)d_ws;
    float* partials = ws;                         // 256*64
    float* newmem = ws + 16384;                   // 64
    unsigned short* wT = (unsigned short*)(ws + 16448);
    unsigned short* w1bT = wT;                    // 16384
    unsigned short* w2bT = wT + 16384;            // 8192
    unsigned short* hw1T = wT + 24576;            // 4096
    unsigned short* hw2T = wT + 28672;            // 512

    prep_weights<<<114, 256, 0, stream>>>(cw1, cw2, hw1, hw2, w1bT, w2bT, hw1T, hw2T);
    fused_main<<<4096, 256, 0, stream>>>(pos, ctx, dep, cw1, cb1, cb2, cw3, cb3,
                                         hw1, hb1, hb2, hw3, hb3,
                                         w1bT, w2bT, hw1T, hw2T, out);
    reduce1<<<256, 256, 0, stream>>>(out, partials);
    reduce2<<<1, 64, 0, stream>>>(partials, cmem, newmem);
    finalize<<<1024, 256, 0, stream>>>(out, newmem);
}